// Round 2
// baseline (175.822 us; speedup 1.0000x reference)
//
#include <hip/hip_runtime.h>
#include <math.h>

#define NROWS 512      // b*c = 8*64
#define NFEAT 4968     // 2*207*12
#define HALF_LOG2PI 0.91893853320467274178032973640562

// ---------------------------------------------------------------------------
// Phase 1: proj[row][48] = dot(x_row, W_j), accumulated in float64.
//   cols 0-15: alpha_w rows, 16-31: sigma_w rows, 32-47: mu_w rows
// Grid: 64 row-blocks * 3 weight-matrices = 192 blocks, 256 threads.
// Thread t: r = t&7 (row in block), j = (t>>3)&15 (component), s = t>>7 (half)
// ---------------------------------------------------------------------------
__global__ __launch_bounds__(256) void proj_kernel(
    const float* __restrict__ x,
    const float* __restrict__ aw,
    const float* __restrict__ sw,
    const float* __restrict__ mw,
    double* __restrict__ proj)
{
    const int blk = blockIdx.x;
    const int jgroup = blk % 3;        // which weight matrix
    const int rowblock = blk / 3;      // 0..63
    const int t = threadIdx.x;
    const int r = t & 7;
    const int j = (t >> 3) & 15;
    const int s = t >> 7;              // 0..1, each half = 2484 floats = 621 float4
    const int row = rowblock * 8 + r;

    const float* W = (jgroup == 0) ? aw : (jgroup == 1) ? sw : mw;
    const float4* xp = (const float4*)(x + (size_t)row * NFEAT + s * 2484);
    const float4* wp = (const float4*)(W + (size_t)j * NFEAT + s * 2484);

    double a0 = 0.0, a1 = 0.0, a2 = 0.0, a3 = 0.0;
    #pragma unroll 2
    for (int i = 0; i < 621; ++i) {
        float4 xv = xp[i], wv = wp[i];
        a0 = fma((double)xv.x, (double)wv.x, a0);
        a1 = fma((double)xv.y, (double)wv.y, a1);
        a2 = fma((double)xv.z, (double)wv.z, a2);
        a3 = fma((double)xv.w, (double)wv.w, a3);
    }
    double a = (a0 + a1) + (a2 + a3);

    __shared__ double part[256];
    part[t] = a;
    __syncthreads();
    if (t < 128) {
        double tot = part[t] + part[t + 128];
        int rr = t & 7, jj = t >> 3;
        proj[(size_t)(rowblock * 8 + rr) * 48 + jgroup * 16 + jj] = tot;
    }
}

// ---------------------------------------------------------------------------
// Phase 2: per-(b,c) row GMM pass. One block per row, 256 threads.
// Decision path (lp, argmax, output norm) in float64; loss path in fp32.
// ---------------------------------------------------------------------------
__global__ __launch_bounds__(256) void gmm_kernel(
    const float* __restrict__ x,
    const double* __restrict__ proj,
    const float* __restrict__ ab,
    const float* __restrict__ sb,
    const float* __restrict__ mb,
    float* __restrict__ out,
    float* __restrict__ part_kl,
    float* __restrict__ part_fi)
{
    const int row = blockIdx.x;
    const int tid = threadIdx.x;

    __shared__ double mu_s[16], isg_s[16], cl_s[16];
    __shared__ double sig_s[16], ivp_s[16];
    __shared__ float  la_s[16], al_s[16];
    __shared__ float  red[4][18];
    __shared__ float  tot_s[18];
    __shared__ float  kl_s[16];

    // --- per-row component parameter setup (threads 0..15, all in wave 0) ---
    if (tid < 16) {
        int k = tid;
        double pa = proj[row * 48 + k]      + (double)ab[k];
        double ps = proj[row * 48 + 16 + k] + (double)sb[k];
        double pm = proj[row * 48 + 32 + k] + (double)mb[k];

        // softmax over 16 components (max-subtracted, like jax.nn.softmax)
        double m = pa;
        #pragma unroll
        for (int off = 8; off; off >>= 1) m = fmax(m, __shfl_xor(m, off, 16));
        double e = exp(pa - m);
        double ss = e;
        #pragma unroll
        for (int off = 8; off; off >>= 1) ss += __shfl_xor(ss, off, 16);
        double alpha = e / ss;
        double la = log(alpha);

        double sg  = exp(ps);
        double lsg = log(sg);

        mu_s[k]  = pm;
        isg_s[k] = 1.0 / sg;
        cl_s[k]  = la - lsg - HALF_LOG2PI;   // lp = cl - 0.5*z^2
        sig_s[k] = sg;
        ivp_s[k] = 1.0 / (sg + 1e-5);
        la_s[k]  = (float)la;
        al_s[k]  = (float)alpha;
    }
    __syncthreads();

    // hoist per-k params to registers (statically indexed -> VGPRs)
    double mu_r[16], isg_r[16], cl_r[16];
    float  la_r[16];
    #pragma unroll
    for (int k = 0; k < 16; ++k) {
        mu_r[k] = mu_s[k]; isg_r[k] = isg_s[k];
        cl_r[k] = cl_s[k]; la_r[k] = la_s[k];
    }

    float S1[16];                         // sum_n lcp_k  (per k)
    #pragma unroll
    for (int k = 0; k < 16; ++k) S1[k] = 0.f;
    float S2 = 0.f;                       // sum_n log_sum
    float FI = 0.f;                       // sum_n sum_k r_k*lcp_k

    const float* xr = x + (size_t)row * NFEAT;
    float* outr = out + (size_t)row * NFEAT;

    for (int n = tid; n < NFEAT; n += 256) {
        double h = (double)xr[n];
        double maxlp = -1.0e300;
        int lab = 0;
        float sumexp = 0.f, s1 = 0.f;
        #pragma unroll
        for (int k = 0; k < 16; ++k) {
            double z  = (h - mu_r[k]) * isg_r[k];
            double lp = fma(z * z, -0.5, cl_r[k]);       // log_prob_k (f64)
            if (lp > maxlp) { maxlp = lp; lab = k; }     // first-max-wins argmax
            float lpf = (float)lp;
            float e   = __expf(lpf);                     // loss path: fast fp32
            float lcp = lpf - la_r[k];                   // log_component_prob
            sumexp += e;
            s1 = fmaf(e, lcp, s1);
            S1[k] += lcp;
        }
        S2 += __logf(sumexp);        // log-sum-exp WITHOUT max-sub (matches ref)
        FI += s1 / sumexp;           // sum_k exp(lp-ls)*lcp

        double sg = sig_s[lab];
        outr[n] = (float)((h - sg) * ivp_s[lab]);
    }

    // --- block-reduce 18 accumulators ---
    float vals[18];
    #pragma unroll
    for (int i = 0; i < 16; ++i) vals[i] = S1[i];
    vals[16] = S2; vals[17] = FI;

    #pragma unroll
    for (int i = 0; i < 18; ++i) {
        float v = vals[i];
        #pragma unroll
        for (int off = 32; off; off >>= 1) v += __shfl_xor(v, off, 64);
        vals[i] = v;
    }
    const int wave = tid >> 6, lane = tid & 63;
    if (lane == 0) {
        #pragma unroll
        for (int i = 0; i < 18; ++i) red[wave][i] = vals[i];
    }
    __syncthreads();
    if (tid < 18)
        tot_s[tid] = red[0][tid] + red[1][tid] + red[2][tid] + red[3][tid];
    __syncthreads();
    if (tid < 16) {
        const float invN = 1.0f / (float)NFEAT;
        // q_z_k = mean_n(lp_k) - mean_n(log_sum) = S1_k/N + la_k - S2/N
        float q = tot_s[tid] * invN + la_s[tid] - tot_s[16] * invN;
        kl_s[tid] = al_s[tid] * (la_s[tid] - q);
    }
    __syncthreads();
    if (tid == 0) {
        float kacc = 0.f;
        #pragma unroll
        for (int i = 0; i < 16; ++i) kacc += kl_s[i];
        part_kl[row] = kacc;
        part_fi[row] = tot_s[17];
    }
}

// ---------------------------------------------------------------------------
// Phase 3: deterministic reduce of 512 row partials -> scalar loss
// ---------------------------------------------------------------------------
__global__ __launch_bounds__(256) void loss_kernel(
    const float* __restrict__ part_kl,
    const float* __restrict__ part_fi,
    float* __restrict__ loss_out)
{
    const int tid = threadIdx.x;
    double a = 0.0, b = 0.0;
    for (int i = tid; i < NROWS; i += 256) {
        a += (double)part_kl[i];
        b += (double)part_fi[i];
    }
    #pragma unroll
    for (int off = 32; off; off >>= 1) {
        a += __shfl_xor(a, off, 64);
        b += __shfl_xor(b, off, 64);
    }
    __shared__ double ra[4], rb[4];
    const int wave = tid >> 6, lane = tid & 63;
    if (lane == 0) { ra[wave] = a; rb[wave] = b; }
    __syncthreads();
    if (tid == 0) {
        double ka = ra[0] + ra[1] + ra[2] + ra[3];
        double kb = rb[0] + rb[1] + rb[2] + rb[3];
        // kl mean over (b,c,K)=8192 ; first_item mean over (b,c,N,K)=40697856
        loss_out[0] = (float)(ka / 8192.0 - kb / 40697856.0);
    }
}

extern "C" void kernel_launch(void* const* d_in, const int* in_sizes, int n_in,
                              void* d_out, int out_size, void* d_ws, size_t ws_size,
                              hipStream_t stream) {
    const float* x  = (const float*)d_in[0];
    const float* aw = (const float*)d_in[1];
    const float* ab = (const float*)d_in[2];
    const float* sw = (const float*)d_in[3];
    const float* sb = (const float*)d_in[4];
    const float* mw = (const float*)d_in[5];
    const float* mb = (const float*)d_in[6];
    float* out = (float*)d_out;

    double* proj   = (double*)d_ws;                    // 512*48 doubles
    float* part_kl = (float*)(proj + NROWS * 48);      // 512 floats
    float* part_fi = part_kl + NROWS;                  // 512 floats

    proj_kernel<<<192, 256, 0, stream>>>(x, aw, sw, mw, proj);
    gmm_kernel<<<NROWS, 256, 0, stream>>>(x, proj, ab, sb, mb, out, part_kl, part_fi);
    loss_kernel<<<1, 256, 0, stream>>>(part_kl, part_fi, out + (size_t)NROWS * NFEAT);
}

// Round 3
// 62.547 us; speedup vs baseline: 2.8111x; 2.8111x over previous
//
#include <hip/hip_runtime.h>
#include <math.h>

#define NROWS 512      // b*c = 8*64
#define NFEAT 4968     // 2*207*12
#define NVEC4 1242     // NFEAT/4 float4 per row
#define HALF_LOG2PI 0.91893853320467274178032973640562

// ---------------------------------------------------------------------------
// Phase 1: proj[row][48] = dot(x_row, W_j), accumulated in float64.
//   cols 0-15: alpha_w rows, 16-31: sigma_w rows, 32-47: mu_w rows
// Grid: 3 jgroups * 512 rows = 1536 blocks (jgroup-major for W L2 locality).
// Thread t: j = t>>4 (component 0..15), s = t&15 (slice).
//   Lane sweep over s -> 16 consecutive float4 per W row (256B contiguous),
//   x float4 broadcast across the 4 j's in a wave. 4 independent f64 chains.
// Reduction over s: in-wave __shfl_xor (width 16), no LDS.
// ---------------------------------------------------------------------------
__global__ __launch_bounds__(256) void proj_kernel(
    const float* __restrict__ x,
    const float* __restrict__ aw,
    const float* __restrict__ sw,
    const float* __restrict__ mw,
    double* __restrict__ proj)
{
    const int jgroup = blockIdx.x >> 9;       // 0..2
    const int row    = blockIdx.x & 511;      // 0..511
    const int t = threadIdx.x;
    const int j = t >> 4;                     // 0..15
    const int s = t & 15;                     // 0..15

    const float* W = (jgroup == 0) ? aw : (jgroup == 1) ? sw : mw;
    const float4* xp = (const float4*)(x + (size_t)row * NFEAT);
    const float4* wp = (const float4*)(W + (size_t)j * NFEAT);

    double a0 = 0.0, a1 = 0.0, a2 = 0.0, a3 = 0.0;
    #pragma unroll 4
    for (int i = s; i < NVEC4; i += 16) {
        float4 xv = xp[i], wv = wp[i];
        a0 = fma((double)xv.x, (double)wv.x, a0);
        a1 = fma((double)xv.y, (double)wv.y, a1);
        a2 = fma((double)xv.z, (double)wv.z, a2);
        a3 = fma((double)xv.w, (double)wv.w, a3);
    }
    double a = (a0 + a1) + (a2 + a3);

    // reduce over s (low 4 lane bits)
    #pragma unroll
    for (int off = 8; off; off >>= 1) a += __shfl_xor(a, off, 16);

    if (s == 0)
        proj[(size_t)row * 48 + jgroup * 16 + j] = a;
}

// ---------------------------------------------------------------------------
// Phase 2: per-(b,c) row GMM pass. One block per row, 256 threads.
// Decision path (lp, argmax, output norm) in float64; loss path in fp32.
// ---------------------------------------------------------------------------
__global__ __launch_bounds__(256) void gmm_kernel(
    const float* __restrict__ x,
    const double* __restrict__ proj,
    const float* __restrict__ ab,
    const float* __restrict__ sb,
    const float* __restrict__ mb,
    float* __restrict__ out,
    float* __restrict__ part_kl,
    float* __restrict__ part_fi)
{
    const int row = blockIdx.x;
    const int tid = threadIdx.x;

    __shared__ double mu_s[16], isg_s[16], cl_s[16];
    __shared__ double sig_s[16], ivp_s[16];
    __shared__ float  la_s[16], al_s[16];
    __shared__ float  red[4][18];
    __shared__ float  tot_s[18];
    __shared__ float  kl_s[16];

    // --- per-row component parameter setup (threads 0..15, all in wave 0) ---
    if (tid < 16) {
        int k = tid;
        double pa = proj[row * 48 + k]      + (double)ab[k];
        double ps = proj[row * 48 + 16 + k] + (double)sb[k];
        double pm = proj[row * 48 + 32 + k] + (double)mb[k];

        // softmax over 16 components (max-subtracted, like jax.nn.softmax)
        double m = pa;
        #pragma unroll
        for (int off = 8; off; off >>= 1) m = fmax(m, __shfl_xor(m, off, 16));
        double e = exp(pa - m);
        double ss = e;
        #pragma unroll
        for (int off = 8; off; off >>= 1) ss += __shfl_xor(ss, off, 16);
        double alpha = e / ss;
        double la = log(alpha);

        double sg  = exp(ps);
        double lsg = log(sg);

        mu_s[k]  = pm;
        isg_s[k] = 1.0 / sg;
        cl_s[k]  = la - lsg - HALF_LOG2PI;   // lp = cl - 0.5*z^2
        sig_s[k] = sg;
        ivp_s[k] = 1.0 / (sg + 1e-5);
        la_s[k]  = (float)la;
        al_s[k]  = (float)alpha;
    }
    __syncthreads();

    // hoist per-k params to registers (statically indexed -> VGPRs)
    double mu_r[16], isg_r[16], cl_r[16];
    float  la_r[16];
    #pragma unroll
    for (int k = 0; k < 16; ++k) {
        mu_r[k] = mu_s[k]; isg_r[k] = isg_s[k];
        cl_r[k] = cl_s[k]; la_r[k] = la_s[k];
    }

    float S1[16];                         // sum_n lcp_k  (per k)
    #pragma unroll
    for (int k = 0; k < 16; ++k) S1[k] = 0.f;
    float S2 = 0.f;                       // sum_n log_sum
    float FI = 0.f;                       // sum_n sum_k r_k*lcp_k

    const float* xr = x + (size_t)row * NFEAT;
    float* outr = out + (size_t)row * NFEAT;

    for (int n = tid; n < NFEAT; n += 256) {
        double h = (double)xr[n];
        double maxlp = -1.0e300;
        int lab = 0;
        float sumexp = 0.f, s1 = 0.f;
        #pragma unroll
        for (int k = 0; k < 16; ++k) {
            double z  = (h - mu_r[k]) * isg_r[k];
            double lp = fma(z * z, -0.5, cl_r[k]);       // log_prob_k (f64)
            if (lp > maxlp) { maxlp = lp; lab = k; }     // first-max-wins argmax
            float lpf = (float)lp;
            float e   = __expf(lpf);                     // loss path: fast fp32
            float lcp = lpf - la_r[k];                   // log_component_prob
            sumexp += e;
            s1 = fmaf(e, lcp, s1);
            S1[k] += lcp;
        }
        S2 += __logf(sumexp);        // log-sum-exp WITHOUT max-sub (matches ref)
        FI += s1 / sumexp;           // sum_k exp(lp-ls)*lcp

        double sg = sig_s[lab];
        outr[n] = (float)((h - sg) * ivp_s[lab]);
    }

    // --- block-reduce 18 accumulators ---
    float vals[18];
    #pragma unroll
    for (int i = 0; i < 16; ++i) vals[i] = S1[i];
    vals[16] = S2; vals[17] = FI;

    #pragma unroll
    for (int i = 0; i < 18; ++i) {
        float v = vals[i];
        #pragma unroll
        for (int off = 32; off; off >>= 1) v += __shfl_xor(v, off, 64);
        vals[i] = v;
    }
    const int wave = tid >> 6, lane = tid & 63;
    if (lane == 0) {
        #pragma unroll
        for (int i = 0; i < 18; ++i) red[wave][i] = vals[i];
    }
    __syncthreads();
    if (tid < 18)
        tot_s[tid] = red[0][tid] + red[1][tid] + red[2][tid] + red[3][tid];
    __syncthreads();
    if (tid < 16) {
        const float invN = 1.0f / (float)NFEAT;
        // q_z_k = mean_n(lp_k) - mean_n(log_sum) = S1_k/N + la_k - S2/N
        float q = tot_s[tid] * invN + la_s[tid] - tot_s[16] * invN;
        kl_s[tid] = al_s[tid] * (la_s[tid] - q);
    }
    __syncthreads();
    if (tid == 0) {
        float kacc = 0.f;
        #pragma unroll
        for (int i = 0; i < 16; ++i) kacc += kl_s[i];
        part_kl[row] = kacc;
        part_fi[row] = tot_s[17];
    }
}

// ---------------------------------------------------------------------------
// Phase 3: deterministic reduce of 512 row partials -> scalar loss
// ---------------------------------------------------------------------------
__global__ __launch_bounds__(256) void loss_kernel(
    const float* __restrict__ part_kl,
    const float* __restrict__ part_fi,
    float* __restrict__ loss_out)
{
    const int tid = threadIdx.x;
    double a = 0.0, b = 0.0;
    for (int i = tid; i < NROWS; i += 256) {
        a += (double)part_kl[i];
        b += (double)part_fi[i];
    }
    #pragma unroll
    for (int off = 32; off; off >>= 1) {
        a += __shfl_xor(a, off, 64);
        b += __shfl_xor(b, off, 64);
    }
    __shared__ double ra[4], rb[4];
    const int wave = tid >> 6, lane = tid & 63;
    if (lane == 0) { ra[wave] = a; rb[wave] = b; }
    __syncthreads();
    if (tid == 0) {
        double ka = ra[0] + ra[1] + ra[2] + ra[3];
        double kb = rb[0] + rb[1] + rb[2] + rb[3];
        // kl mean over (b,c,K)=8192 ; first_item mean over (b,c,N,K)=40697856
        loss_out[0] = (float)(ka / 8192.0 - kb / 40697856.0);
    }
}

extern "C" void kernel_launch(void* const* d_in, const int* in_sizes, int n_in,
                              void* d_out, int out_size, void* d_ws, size_t ws_size,
                              hipStream_t stream) {
    const float* x  = (const float*)d_in[0];
    const float* aw = (const float*)d_in[1];
    const float* ab = (const float*)d_in[2];
    const float* sw = (const float*)d_in[3];
    const float* sb = (const float*)d_in[4];
    const float* mw = (const float*)d_in[5];
    const float* mb = (const float*)d_in[6];
    float* out = (float*)d_out;

    double* proj   = (double*)d_ws;                    // 512*48 doubles
    float* part_kl = (float*)(proj + NROWS * 48);      // 512 floats
    float* part_fi = part_kl + NROWS;                  // 512 floats

    proj_kernel<<<3 * NROWS, 256, 0, stream>>>(x, aw, sw, mw, proj);
    gmm_kernel<<<NROWS, 256, 0, stream>>>(x, proj, ab, sb, mb, out, part_kl, part_fi);
    loss_kernel<<<1, 256, 0, stream>>>(part_kl, part_fi, out + (size_t)NROWS * NFEAT);
}

// Round 4
// 58.179 us; speedup vs baseline: 3.0221x; 1.0751x over previous
//
#include <hip/hip_runtime.h>
#include <math.h>

#define NROWS 512      // b*c = 8*64
#define NFEAT 4968     // 2*207*12
#define NVEC4 1242     // NFEAT/4 float4 per row
#define KSLICES 6
#define SLICE4 207     // float4 per K-slice (1242/6)
#define GSL 1242       // gmm elements per slice (NFEAT/4)
#define HALF_LOG2PI 0.91893853320467274178032973640562

// ---------------------------------------------------------------------------
// Phase 1: split-K row-tiled projection partials.
// pp[row][48][6] (f64). Grid: 64 rowtiles * 3 jgroups * 6 kslices = 1152.
// Thread t: j = t>>4 (component), s16 = t&15. One W float4 per iter is
// reused across 8 rows (acc[8][2] f64 chains).
// ---------------------------------------------------------------------------
__global__ __launch_bounds__(256) void proj_kernel(
    const float* __restrict__ x,
    const float* __restrict__ aw,
    const float* __restrict__ sw,
    const float* __restrict__ mw,
    double* __restrict__ pp)
{
    const int rowtile = blockIdx.x & 63;
    const int jg      = (blockIdx.x >> 6) % 3;
    const int sl      = blockIdx.x / 192;
    const int t = threadIdx.x;
    const int j = t >> 4;
    const int s16 = t & 15;
    const int row0 = rowtile * 8;

    const float* W = (jg == 0) ? aw : (jg == 1) ? sw : mw;
    const float4* wp = (const float4*)(W + (size_t)j * NFEAT) + sl * SLICE4;
    const float4* xp = (const float4*)(x + (size_t)row0 * NFEAT) + sl * SLICE4;

    double acc[8][2];
    #pragma unroll
    for (int r = 0; r < 8; ++r) { acc[r][0] = 0.0; acc[r][1] = 0.0; }

    for (int i = s16; i < SLICE4; i += 16) {
        float4 wv = wp[i];
        #pragma unroll
        for (int r = 0; r < 8; ++r) {
            float4 xv = xp[(size_t)r * NVEC4 + i];
            acc[r][0] = fma((double)xv.x, (double)wv.x, acc[r][0]);
            acc[r][0] = fma((double)xv.y, (double)wv.y, acc[r][0]);
            acc[r][1] = fma((double)xv.z, (double)wv.z, acc[r][1]);
            acc[r][1] = fma((double)xv.w, (double)wv.w, acc[r][1]);
        }
    }

    #pragma unroll
    for (int r = 0; r < 8; ++r) {
        double a = acc[r][0] + acc[r][1];
        #pragma unroll
        for (int off = 8; off; off >>= 1) a += __shfl_xor(a, off, 16);
        if (s16 == 0)
            pp[((size_t)(row0 + r) * 48 + jg * 16 + j) * KSLICES + sl] = a;
    }
}

// ---------------------------------------------------------------------------
// Phase 2: per-(row,k) parameter derivation (f64, exactly as before).
// 8192 items = 32 blocks * 256. lanes 0..15 of each 16-group = k of one row.
// ---------------------------------------------------------------------------
__global__ __launch_bounds__(256) void params_kernel(
    const double* __restrict__ pp,
    const float* __restrict__ ab,
    const float* __restrict__ sb,
    const float* __restrict__ mb,
    double* __restrict__ mu, double* __restrict__ isg, double* __restrict__ cl,
    double* __restrict__ sig, double* __restrict__ ivp,
    float* __restrict__ la, float* __restrict__ al)
{
    const int g = blockIdx.x * 256 + threadIdx.x;   // 0..8191
    const int row = g >> 4, k = g & 15;
    const double* p = pp + ((size_t)row * 48 + k) * KSLICES;

    double pa = 0.0, ps = 0.0, pm = 0.0;
    #pragma unroll
    for (int s = 0; s < KSLICES; ++s) {
        pa += p[s];
        ps += p[16 * KSLICES + s];
        pm += p[32 * KSLICES + s];
    }
    pa += (double)ab[k]; ps += (double)sb[k]; pm += (double)mb[k];

    // softmax over 16 components (max-subtracted, like jax.nn.softmax)
    double m = pa;
    #pragma unroll
    for (int off = 8; off; off >>= 1) m = fmax(m, __shfl_xor(m, off, 16));
    double e = exp(pa - m);
    double ss = e;
    #pragma unroll
    for (int off = 8; off; off >>= 1) ss += __shfl_xor(ss, off, 16);
    double alpha = e / ss;
    double lav = log(alpha);

    double sg  = exp(ps);
    double lsg = log(sg);

    mu[g]  = pm;
    isg[g] = 1.0 / sg;
    cl[g]  = lav - lsg - HALF_LOG2PI;   // lp = cl - 0.5*z^2
    sig[g] = sg;
    ivp[g] = 1.0 / (sg + 1e-5);
    la[g]  = (float)lav;
    al[g]  = (float)alpha;
}

// ---------------------------------------------------------------------------
// Phase 3: GMM pass, 4 slices per row -> 2048 blocks * 256 threads.
// Decision path identical to the passing kernel (f64 lp, first-max argmax).
// ---------------------------------------------------------------------------
__global__ __launch_bounds__(256) void gmm_kernel(
    const float* __restrict__ x,
    const double* __restrict__ mu, const double* __restrict__ isg,
    const double* __restrict__ cl, const float* __restrict__ laf,
    const double* __restrict__ sig, const double* __restrict__ ivp,
    float* __restrict__ out,
    float* __restrict__ S1p, float* __restrict__ S2p, float* __restrict__ FIp)
{
    const int row = blockIdx.x >> 2;
    const int sl  = blockIdx.x & 3;
    const int tid = threadIdx.x;
    const int g0  = row * 16;

    __shared__ double sig_s[16], ivp_s[16];
    __shared__ float  red[4][18];
    __shared__ float  tot_s[18];

    if (tid < 16) {
        sig_s[tid] = sig[g0 + tid];
        ivp_s[tid] = ivp[g0 + tid];
    }
    __syncthreads();

    double mu_r[16], isg_r[16], cl_r[16];
    float  la_r[16];
    #pragma unroll
    for (int k = 0; k < 16; ++k) {
        mu_r[k]  = mu[g0 + k];
        isg_r[k] = isg[g0 + k];
        cl_r[k]  = cl[g0 + k];
        la_r[k]  = laf[g0 + k];
    }

    float S1[16];
    #pragma unroll
    for (int k = 0; k < 16; ++k) S1[k] = 0.f;
    float S2 = 0.f, FI = 0.f;

    const float* xr = x + (size_t)row * NFEAT + sl * GSL;
    float* outr = out + (size_t)row * NFEAT + sl * GSL;

    for (int n = tid; n < GSL; n += 256) {
        double h = (double)xr[n];
        double maxlp = -1.0e300;
        int lab = 0;
        float sumexp = 0.f, s1 = 0.f;
        #pragma unroll
        for (int k = 0; k < 16; ++k) {
            double z  = (h - mu_r[k]) * isg_r[k];
            double lp = fma(z * z, -0.5, cl_r[k]);       // log_prob_k (f64)
            if (lp > maxlp) { maxlp = lp; lab = k; }     // first-max-wins argmax
            float lpf = (float)lp;
            float e   = __expf(lpf);                     // loss path: fast fp32
            float lcp = lpf - la_r[k];                   // log_component_prob
            sumexp += e;
            s1 = fmaf(e, lcp, s1);
            S1[k] += lcp;
        }
        S2 += __logf(sumexp);        // log-sum-exp WITHOUT max-sub (matches ref)
        FI += s1 / sumexp;

        double sg = sig_s[lab];
        outr[n] = (float)((h - sg) * ivp_s[lab]);
    }

    // --- block-reduce 18 accumulators ---
    float vals[18];
    #pragma unroll
    for (int i = 0; i < 16; ++i) vals[i] = S1[i];
    vals[16] = S2; vals[17] = FI;

    #pragma unroll
    for (int i = 0; i < 18; ++i) {
        float v = vals[i];
        #pragma unroll
        for (int off = 32; off; off >>= 1) v += __shfl_xor(v, off, 64);
        vals[i] = v;
    }
    const int wave = tid >> 6, lane = tid & 63;
    if (lane == 0) {
        #pragma unroll
        for (int i = 0; i < 18; ++i) red[wave][i] = vals[i];
    }
    __syncthreads();
    if (tid < 18)
        tot_s[tid] = red[0][tid] + red[1][tid] + red[2][tid] + red[3][tid];
    __syncthreads();
    if (tid < 16) S1p[(size_t)blockIdx.x * 16 + tid] = tot_s[tid];
    if (tid == 16) S2p[blockIdx.x] = tot_s[16];
    if (tid == 17) FIp[blockIdx.x] = tot_s[17];
}

// ---------------------------------------------------------------------------
// Phase 4: single-block deterministic loss reduce.
// ---------------------------------------------------------------------------
__global__ __launch_bounds__(1024) void loss_kernel(
    const float* __restrict__ S1p, const float* __restrict__ S2p,
    const float* __restrict__ FIp,
    const float* __restrict__ la, const float* __restrict__ al,
    float* __restrict__ loss_out)
{
    const int tid = threadIdx.x;
    const float invN = 1.0f / (float)NFEAT;

    float kl_acc = 0.f;
    for (int g = tid; g < 8192; g += 1024) {
        int row = g >> 4, k = g & 15;
        int b = row * 4;
        float s1 = S1p[(size_t)(b + 0) * 16 + k] + S1p[(size_t)(b + 1) * 16 + k]
                 + S1p[(size_t)(b + 2) * 16 + k] + S1p[(size_t)(b + 3) * 16 + k];
        float s2 = S2p[b + 0] + S2p[b + 1] + S2p[b + 2] + S2p[b + 3];
        float lav = la[g], alv = al[g];
        float q = s1 * invN + lav - s2 * invN;
        kl_acc += alv * (lav - q);
    }
    float fi_acc = 0.f;
    for (int i = tid; i < 2048; i += 1024) fi_acc += FIp[i];

    #pragma unroll
    for (int off = 32; off; off >>= 1) {
        kl_acc += __shfl_xor(kl_acc, off, 64);
        fi_acc += __shfl_xor(fi_acc, off, 64);
    }
    __shared__ float ra[16], rb[16];
    const int wave = tid >> 6, lane = tid & 63;
    if (lane == 0) { ra[wave] = kl_acc; rb[wave] = fi_acc; }
    __syncthreads();
    if (tid == 0) {
        float ka = 0.f, kb = 0.f;
        #pragma unroll
        for (int i = 0; i < 16; ++i) { ka += ra[i]; kb += rb[i]; }
        // kl mean over (b,c,K)=8192 ; first_item mean over (b,c,N,K)=40697856
        loss_out[0] = ka / 8192.0f - kb / 40697856.0f;
    }
}

extern "C" void kernel_launch(void* const* d_in, const int* in_sizes, int n_in,
                              void* d_out, int out_size, void* d_ws, size_t ws_size,
                              hipStream_t stream) {
    const float* x  = (const float*)d_in[0];
    const float* aw = (const float*)d_in[1];
    const float* ab = (const float*)d_in[2];
    const float* sw = (const float*)d_in[3];
    const float* sb = (const float*)d_in[4];
    const float* mw = (const float*)d_in[5];
    const float* mb = (const float*)d_in[6];
    float* out = (float*)d_out;

    double* pp  = (double*)d_ws;            // 512*48*6 = 147456 doubles
    double* mu  = pp + (size_t)NROWS * 48 * KSLICES;
    double* isg = mu + 8192;
    double* cl  = isg + 8192;
    double* sig = cl + 8192;
    double* ivp = sig + 8192;
    float* la   = (float*)(ivp + 8192);
    float* al   = la + 8192;
    float* S1p  = al + 8192;                // 2048*16
    float* S2p  = S1p + 2048 * 16;          // 2048
    float* FIp  = S2p + 2048;               // 2048

    proj_kernel<<<64 * 3 * KSLICES, 256, 0, stream>>>(x, aw, sw, mw, pp);
    params_kernel<<<32, 256, 0, stream>>>(pp, ab, sb, mb, mu, isg, cl, sig, ivp, la, al);
    gmm_kernel<<<NROWS * 4, 256, 0, stream>>>(x, mu, isg, cl, la, sig, ivp,
                                              out, S1p, S2p, FIp);
    loss_kernel<<<1, 1024, 0, stream>>>(S1p, S2p, FIp, la, al,
                                        out + (size_t)NROWS * NFEAT);
}